// Round 2
// baseline (20099.684 us; speedup 1.0000x reference)
//
#include <hip/hip_runtime.h>
#include <cstdint>
#include <cstddef>

// ---------------------------------------------------------------------------
// GumbelRNNGenerator persistent-kernel implementation.
// B=128, NOISE=128, H=512, V=5000, T=128 sequential steps, all fp32.
// One kernel, 256 blocks (1/CU), grid barriers between per-step stages.
// ---------------------------------------------------------------------------
#define B_SZ 128
#define NOISE_SZ 128
#define H 512
#define V_SZ 5000
#define BN_EPS 1e-5f
#define NBLK 256
#define NTHR 256

// workspace offsets (in floats)
#define XBUF_OFF 0            // [128][512] lrelu(emb[prev]) raw (pre-BN)
#define H_OFF    65536        // [128][512] hidden state
#define O_OFF    131072       // [128][512] bn(lrelu(h)) / setup scratch si_z
#define SIX_OFF  196608       // [128][512] bn(concat)[:, :512]; aliases zbn in setup
#define GI_OFF   262144       // [128][1536]
#define GH_OFF   458752       // [128][1536]
#define GIZ_OFF  655360       // [128][1536] si_z @ W_ih[:,512:]^T + b_ih
#define BAR_OFF  851968       // barrier state (uints), 1024 dwords

// ------------------------------- Threefry ---------------------------------
__device__ __forceinline__ uint32_t rotl32(uint32_t v, int r) {
  return (v << r) | (v >> (32 - r));
}

__device__ __forceinline__ void threefry2x32(uint32_t k0, uint32_t k1,
                                             uint32_t x0, uint32_t x1,
                                             uint32_t& o0, uint32_t& o1) {
  uint32_t k2 = k0 ^ k1 ^ 0x1BD11BDAu;
  x0 += k0; x1 += k1;
#define TFR(r) { x0 += x1; x1 = rotl32(x1, (r)); x1 ^= x0; }
  TFR(13) TFR(15) TFR(26) TFR(6)
  x0 += k1; x1 += k2 + 1u;
  TFR(17) TFR(29) TFR(16) TFR(24)
  x0 += k2; x1 += k0 + 2u;
  TFR(13) TFR(15) TFR(26) TFR(6)
  x0 += k0; x1 += k1 + 3u;
  TFR(17) TFR(29) TFR(16) TFR(24)
  x0 += k1; x1 += k2 + 4u;
  TFR(13) TFR(15) TFR(26) TFR(6)
  x0 += k2; x1 += k0 + 5u;
#undef TFR
  o0 = x0; o1 = x1;
}

// compile-time subkey chain: jax.random.key(42), partitionable fold-in split
struct U2 { uint32_t a, b; };
constexpr U2 tf_c(uint32_t k0, uint32_t k1, uint32_t x0, uint32_t x1) {
  uint32_t k2 = k0 ^ k1 ^ 0x1BD11BDAu;
  x0 += k0; x1 += k1;
#define TFRC(r) { x0 += x1; x1 = (uint32_t)((x1 << (r)) | (x1 >> (32 - (r)))); x1 ^= x0; }
  TFRC(13) TFRC(15) TFRC(26) TFRC(6)
  x0 += k1; x1 += k2 + 1u;
  TFRC(17) TFRC(29) TFRC(16) TFRC(24)
  x0 += k2; x1 += k0 + 2u;
  TFRC(13) TFRC(15) TFRC(26) TFRC(6)
  x0 += k0; x1 += k1 + 3u;
  TFRC(17) TFRC(29) TFRC(16) TFRC(24)
  x0 += k1; x1 += k2 + 4u;
  TFRC(13) TFRC(15) TFRC(26) TFRC(6)
  x0 += k2; x1 += k0 + 5u;
#undef TFRC
  return U2{x0, x1};
}

struct SubKeys { uint32_t v[512]; };
constexpr SubKeys make_subkeys() {
  SubKeys s{};
  uint32_t k0 = 0u, k1 = 42u;
  for (int t = 0; t < 256; ++t) {
    U2 nk = tf_c(k0, k1, 0u, 0u);   // new key
    U2 sb = tf_c(k0, k1, 0u, 1u);   // subkey
    s.v[2 * t] = sb.a; s.v[2 * t + 1] = sb.b;
    k0 = nk.a; k1 = nk.b;
  }
  return s;
}
__device__ __constant__ SubKeys SUBK = make_subkeys();

__device__ __forceinline__ float lrelu_(float x) { return x >= 0.f ? x : 0.2f * x; }
__device__ __forceinline__ float sigmoidf_(float x) {
  return (x >= 0.f) ? 1.f / (1.f + expf(-x)) : expf(x) / (1.f + expf(x));
}

// --------------------------- grid barrier ----------------------------------
// Two-level: 16 group counters (64B apart) -> master -> generation flag.
// Release via __threadfence() (agent-scope: L2 writeback) before gen store;
// waiters spin relaxed then __threadfence() (acquire: cache invalidate).
__device__ __forceinline__ void gridbar(uint32_t* bw) {
  __syncthreads();
  if (threadIdx.x == 0) {
    __threadfence();  // publish this block's writes
    uint32_t* gcnt = bw + ((blockIdx.x & 15) << 4);
    uint32_t* master = bw + 256;
    uint32_t* genp = bw + 272;
    uint32_t g = __hip_atomic_load(genp, __ATOMIC_RELAXED, __HIP_MEMORY_SCOPE_AGENT);
    uint32_t p = __hip_atomic_fetch_add(gcnt, 1u, __ATOMIC_RELAXED, __HIP_MEMORY_SCOPE_AGENT);
    bool released = false;
    if (p == 15u) {
      uint32_t pm = __hip_atomic_fetch_add(master, 1u, __ATOMIC_RELAXED, __HIP_MEMORY_SCOPE_AGENT);
      if (pm == 15u) {  // last arriver: reset counters, bump generation
        for (int i = 0; i < 16; ++i)
          __hip_atomic_store(bw + (i << 4), 0u, __ATOMIC_RELAXED, __HIP_MEMORY_SCOPE_AGENT);
        __hip_atomic_store(master, 0u, __ATOMIC_RELAXED, __HIP_MEMORY_SCOPE_AGENT);
        __threadfence();
        __hip_atomic_store(genp, g + 1u, __ATOMIC_RELAXED, __HIP_MEMORY_SCOPE_AGENT);
        released = true;
      }
    }
    if (!released) {
      while (__hip_atomic_load(genp, __ATOMIC_RELAXED, __HIP_MEMORY_SCOPE_AGENT) == g)
        __builtin_amdgcn_s_sleep(2);
    }
    __threadfence();  // acquire: see other blocks' writes
  }
  __syncthreads();
}

// ------------------------- GEMM 32x64 tile ---------------------------------
// C[m0:m0+32, n0:n0+64] = A[32xK] @ W[64xK]^T + (full ? full : bias), opt lrelu.
// A row-major [128][lda], W row-major [N][ldw]. K % 32 == 0, N-tile fully valid.
__device__ __forceinline__ void gemm32x64(
    const float* __restrict__ A, int lda,
    const float* __restrict__ W, int ldw, int K,
    int m0, int n0,
    const float* __restrict__ bias,
    const float* __restrict__ full, int fullld,
    bool relu,
    float* __restrict__ C, int ldc,
    float* smem) {
  float* As = smem;           // [32][38]
  float* Ws = smem + 1216;    // [32][68]
  const int tid = threadIdx.x;
  const int tn = tid & 15, tm = tid >> 4;
  const int amr = tid >> 3, aq = tid & 7;   // A stager: row, k-quad
  const int wnr = tid >> 2, wq = tid & 3;   // W stager: row, k-quad pair
  float acc[2][4] = {{0.f,0.f,0.f,0.f},{0.f,0.f,0.f,0.f}};
  for (int k0 = 0; k0 < K; k0 += 32) {
    const float4 av = *(const float4*)&A[(size_t)(m0 + amr) * lda + k0 + aq * 4];
    const float4 w0 = *(const float4*)&W[(size_t)(n0 + wnr) * ldw + k0 + wq * 4];
    const float4 w1 = *(const float4*)&W[(size_t)(n0 + wnr) * ldw + k0 + 16 + wq * 4];
    As[(aq * 4 + 0) * 38 + amr] = av.x;
    As[(aq * 4 + 1) * 38 + amr] = av.y;
    As[(aq * 4 + 2) * 38 + amr] = av.z;
    As[(aq * 4 + 3) * 38 + amr] = av.w;
    Ws[(wq * 4 + 0) * 68 + wnr] = w0.x;
    Ws[(wq * 4 + 1) * 68 + wnr] = w0.y;
    Ws[(wq * 4 + 2) * 68 + wnr] = w0.z;
    Ws[(wq * 4 + 3) * 68 + wnr] = w0.w;
    Ws[(16 + wq * 4 + 0) * 68 + wnr] = w1.x;
    Ws[(16 + wq * 4 + 1) * 68 + wnr] = w1.y;
    Ws[(16 + wq * 4 + 2) * 68 + wnr] = w1.z;
    Ws[(16 + wq * 4 + 3) * 68 + wnr] = w1.w;
    __syncthreads();
#pragma unroll
    for (int kk = 0; kk < 32; ++kk) {
      const float2 a2 = *(const float2*)&As[kk * 38 + tm * 2];
      const float4 b4 = *(const float4*)&Ws[kk * 68 + tn * 4];
      acc[0][0] = fmaf(a2.x, b4.x, acc[0][0]);
      acc[0][1] = fmaf(a2.x, b4.y, acc[0][1]);
      acc[0][2] = fmaf(a2.x, b4.z, acc[0][2]);
      acc[0][3] = fmaf(a2.x, b4.w, acc[0][3]);
      acc[1][0] = fmaf(a2.y, b4.x, acc[1][0]);
      acc[1][1] = fmaf(a2.y, b4.y, acc[1][1]);
      acc[1][2] = fmaf(a2.y, b4.z, acc[1][2]);
      acc[1][3] = fmaf(a2.y, b4.w, acc[1][3]);
    }
    __syncthreads();
  }
#pragma unroll
  for (int i = 0; i < 2; ++i) {
    const int m = m0 + tm * 2 + i;
#pragma unroll
    for (int j = 0; j < 4; ++j) {
      const int n = n0 + tn * 4 + j;
      float v = acc[i][j] + (full ? full[(size_t)m * fullld + n] : bias[n]);
      if (relu) v = lrelu_(v);
      C[(size_t)m * ldc + n] = v;
    }
  }
}

// -------------------- GEMM 32x80 logits + gumbel epilogue ------------------
// Writes y = ((o@W^T + b) + gumbel)/temp straight into out[(m*T + t)*V + n].
__device__ __forceinline__ void gemm32x80_logits(
    const float* __restrict__ A, const float* __restrict__ W,
    const float* __restrict__ bias, int m0, int n0,
    float* __restrict__ out, int t, int T,
    const float* __restrict__ temp_ptr, float* smem) {
  float* As = smem;            // [32][38]
  float* Ws2 = smem + 1216;    // [32][84]
  const int tid = threadIdx.x;
  const int tn = tid & 15, tm = tid >> 4;
  const int amr = tid >> 3, aq = tid & 7;
  const int wnr = tid >> 2, wq = tid & 3;
  const int pn = 64 + (tid >> 3), pq = tid & 7;   // part-2 stager (tid<128)
  float acc[2][5] = {{0,0,0,0,0},{0,0,0,0,0}};
  for (int k0 = 0; k0 < 512; k0 += 32) {
    const float4 av = *(const float4*)&A[(size_t)(m0 + amr) * 512 + k0 + aq * 4];
    float4 w0 = {0,0,0,0}, w1 = {0,0,0,0}, w2 = {0,0,0,0};
    if (n0 + wnr < V_SZ) {
      w0 = *(const float4*)&W[(size_t)(n0 + wnr) * 512 + k0 + wq * 4];
      w1 = *(const float4*)&W[(size_t)(n0 + wnr) * 512 + k0 + 16 + wq * 4];
    }
    if (tid < 128 && n0 + pn < V_SZ)
      w2 = *(const float4*)&W[(size_t)(n0 + pn) * 512 + k0 + pq * 4];
    As[(aq * 4 + 0) * 38 + amr] = av.x;
    As[(aq * 4 + 1) * 38 + amr] = av.y;
    As[(aq * 4 + 2) * 38 + amr] = av.z;
    As[(aq * 4 + 3) * 38 + amr] = av.w;
    Ws2[(wq * 4 + 0) * 84 + wnr] = w0.x;
    Ws2[(wq * 4 + 1) * 84 + wnr] = w0.y;
    Ws2[(wq * 4 + 2) * 84 + wnr] = w0.z;
    Ws2[(wq * 4 + 3) * 84 + wnr] = w0.w;
    Ws2[(16 + wq * 4 + 0) * 84 + wnr] = w1.x;
    Ws2[(16 + wq * 4 + 1) * 84 + wnr] = w1.y;
    Ws2[(16 + wq * 4 + 2) * 84 + wnr] = w1.z;
    Ws2[(16 + wq * 4 + 3) * 84 + wnr] = w1.w;
    if (tid < 128) {
      Ws2[(pq * 4 + 0) * 84 + pn] = w2.x;
      Ws2[(pq * 4 + 1) * 84 + pn] = w2.y;
      Ws2[(pq * 4 + 2) * 84 + pn] = w2.z;
      Ws2[(pq * 4 + 3) * 84 + pn] = w2.w;
    }
    __syncthreads();
#pragma unroll
    for (int kk = 0; kk < 32; ++kk) {
      const float2 a2 = *(const float2*)&As[kk * 38 + tm * 2];
      const float4 b4 = *(const float4*)&Ws2[kk * 84 + tn * 4];
      const float b1 = Ws2[kk * 84 + 64 + tn];
      acc[0][0] = fmaf(a2.x, b4.x, acc[0][0]);
      acc[0][1] = fmaf(a2.x, b4.y, acc[0][1]);
      acc[0][2] = fmaf(a2.x, b4.z, acc[0][2]);
      acc[0][3] = fmaf(a2.x, b4.w, acc[0][3]);
      acc[0][4] = fmaf(a2.x, b1,   acc[0][4]);
      acc[1][0] = fmaf(a2.y, b4.x, acc[1][0]);
      acc[1][1] = fmaf(a2.y, b4.y, acc[1][1]);
      acc[1][2] = fmaf(a2.y, b4.z, acc[1][2]);
      acc[1][3] = fmaf(a2.y, b4.w, acc[1][3]);
      acc[1][4] = fmaf(a2.y, b1,   acc[1][4]);
    }
    __syncthreads();
  }
  const float temp = temp_ptr[0];
  const uint32_t sk0 = SUBK.v[2 * t], sk1 = SUBK.v[2 * t + 1];
#pragma unroll
  for (int i = 0; i < 2; ++i) {
    const int m = m0 + tm * 2 + i;
    float* rowp = out + ((size_t)m * T + t) * V_SZ;
#pragma unroll
    for (int j = 0; j < 5; ++j) {
      const int n = (j < 4) ? (n0 + tn * 4 + j) : (n0 + 64 + tn);
      if (n < V_SZ) {
        const float logit = acc[i][j] + bias[n];
        uint32_t r0, r1;
        threefry2x32(sk0, sk1, 0u, (uint32_t)(m * V_SZ + n), r0, r1);
        const uint32_t bits = r0 ^ r1;
        const float f = __uint_as_float((bits >> 9) | 0x3f800000u) - 1.0f;
        const float u = fmaxf(1e-20f, f + 1e-20f);
        const float gum = -logf(-logf(u));
        rowp[n] = (logit + gum) / temp;
      }
    }
  }
}

// ------------------- BN over batch, 8 cols per block -----------------------
// in/out [128][512]. Cols c0..c0+7; 32 threads/col, 4 rows/thread, shfl reduce.
__device__ __forceinline__ void bn8(const float* __restrict__ in,
                                    const float* __restrict__ g,
                                    const float* __restrict__ be,
                                    float* __restrict__ outp,
                                    float* __restrict__ out2, int c0) {
  const int col = c0 + (threadIdx.x >> 5);
  const int r = threadIdx.x & 31;
  float x0 = in[(size_t)r * H + col];
  float x1 = in[(size_t)(r + 32) * H + col];
  float x2 = in[(size_t)(r + 64) * H + col];
  float x3 = in[(size_t)(r + 96) * H + col];
  float s = x0 + x1 + x2 + x3;
#pragma unroll
  for (int m = 16; m; m >>= 1) s += __shfl_xor(s, m);
  const float mean = s * (1.f / 128.f);
  const float d0 = x0 - mean, d1 = x1 - mean, d2 = x2 - mean, d3 = x3 - mean;
  float q = d0 * d0 + d1 * d1 + d2 * d2 + d3 * d3;
#pragma unroll
  for (int m = 16; m; m >>= 1) q += __shfl_xor(q, m);
  const float v = q * (1.f / 128.f);
  const float sd = sqrtf(v + BN_EPS);
  const float gc = g[col], bc = be[col];
  float y0 = gc * d0 / sd + bc;
  float y1 = gc * d1 / sd + bc;
  float y2 = gc * d2 / sd + bc;
  float y3 = gc * d3 / sd + bc;
  outp[(size_t)r * H + col] = y0;
  outp[(size_t)(r + 32) * H + col] = y1;
  outp[(size_t)(r + 64) * H + col] = y2;
  outp[(size_t)(r + 96) * H + col] = y3;
  if (out2) {
    out2[(size_t)r * H + col] = y0;
    out2[(size_t)(r + 32) * H + col] = y1;
    out2[(size_t)(r + 64) * H + col] = y2;
    out2[(size_t)(r + 96) * H + col] = y3;
  }
}

// ----------------- GRU gates + h update + BN(lrelu(h)) -> o ----------------
__device__ __forceinline__ void gru8(const float* __restrict__ gi,
                                     const float* __restrict__ gh,
                                     float* __restrict__ h,
                                     const float* __restrict__ g3,
                                     const float* __restrict__ be3,
                                     float* __restrict__ o, int c0) {
  const int col = c0 + (threadIdx.x >> 5);
  const int r = threadIdx.x & 31;
  float x[4];
#pragma unroll
  for (int i = 0; i < 4; ++i) {
    const int b = r + 32 * i;
    const float* gib = gi + (size_t)b * 1536;
    const float* ghb = gh + (size_t)b * 1536;
    const float rr = sigmoidf_(gib[col] + ghb[col]);
    const float zt = sigmoidf_(gib[512 + col] + ghb[512 + col]);
    const float nn = tanhf(gib[1024 + col] + rr * ghb[1024 + col]);
    const float hold = h[(size_t)b * H + col];
    const float hnew = (1.f - zt) * nn + zt * hold;
    h[(size_t)b * H + col] = hnew;
    x[i] = lrelu_(hnew);
  }
  float s = x[0] + x[1] + x[2] + x[3];
#pragma unroll
  for (int m = 16; m; m >>= 1) s += __shfl_xor(s, m);
  const float mean = s * (1.f / 128.f);
  float q = 0.f;
#pragma unroll
  for (int i = 0; i < 4; ++i) { const float d = x[i] - mean; q += d * d; }
#pragma unroll
  for (int m = 16; m; m >>= 1) q += __shfl_xor(q, m);
  const float v = q * (1.f / 128.f);
  const float sd = sqrtf(v + BN_EPS);
  const float gc = g3[col], bc = be3[col];
#pragma unroll
  for (int i = 0; i < 4; ++i) {
    const int b = r + 32 * i;
    o[(size_t)b * H + col] = gc * (x[i] - mean) / sd + bc;
  }
}

// --------- softmax + argmax + next-token embedding gather (1 row) ----------
__device__ __forceinline__ void gumbel_row(float* __restrict__ out, int t, int T, int b,
                                           const float* __restrict__ emb,
                                           float* __restrict__ xbuf, float* smem) {
  float* sy = smem;                      // [5000]
  float* red = smem + 5000;              // [256]
  int* redi = (int*)(smem + 5256);       // [256]
  int* swin = (int*)(smem + 5512);       // [1]
  const int tid = threadIdx.x;
  float* row = out + ((size_t)b * T + t) * V_SZ;   // y written by logits stage

  float lmax = -3.4e38f;
  for (int j = tid; j < V_SZ; j += NTHR) {
    const float y = row[j];
    sy[j] = y;
    lmax = fmaxf(lmax, y);
  }
  red[tid] = lmax; __syncthreads();
#pragma unroll
  for (int s = 128; s > 0; s >>= 1) {
    if (tid < s) red[tid] = fmaxf(red[tid], red[tid + s]);
    __syncthreads();
  }
  const float m = red[0];
  __syncthreads();

  float lsum = 0.f;
  for (int j = tid; j < V_SZ; j += NTHR) {
    const float e = expf(sy[j] - m); sy[j] = e; lsum += e;
  }
  red[tid] = lsum; __syncthreads();
#pragma unroll
  for (int s = 128; s > 0; s >>= 1) {
    if (tid < s) red[tid] += red[tid + s];
    __syncthreads();
  }
  const float S = red[0];
  __syncthreads();

  float bmax = -1.f; int bidx = 0x7fffffff;
  for (int j = tid; j < V_SZ; j += NTHR) {
    const float p = sy[j] / S;
    row[j] = p;
    if (p > bmax) { bmax = p; bidx = j; }
  }
  red[tid] = bmax; redi[tid] = bidx; __syncthreads();
#pragma unroll
  for (int s = 128; s > 0; s >>= 1) {
    if (tid < s) {
      const float v2 = red[tid + s]; const int i2 = redi[tid + s];
      if (v2 > red[tid] || (v2 == red[tid] && i2 < redi[tid])) { red[tid] = v2; redi[tid] = i2; }
    }
    __syncthreads();
  }
  if (tid == 0) swin[0] = redi[0];
  __syncthreads();
  const int idx = swin[0];
  // next step's pre-BN input: lrelu(emb[idx])
  const float* er = emb + (size_t)idx * H;
  xbuf[(size_t)b * H + tid] = lrelu_(er[tid]);
  xbuf[(size_t)b * H + NTHR + tid] = lrelu_(er[NTHR + tid]);
}

// ------------------------------ the kernel ---------------------------------
__global__ __launch_bounds__(NTHR, 2) void persist(
    const float* __restrict__ z, const float* __restrict__ temp,
    const float* __restrict__ W_z2h, const float* __restrict__ b_z2h,
    const float* __restrict__ g1, const float* __restrict__ be1,
    const float* __restrict__ emb,
    const float* __restrict__ g2, const float* __restrict__ be2,
    const float* __restrict__ W_ih, const float* __restrict__ b_ih,
    const float* __restrict__ W_hh, const float* __restrict__ b_hh,
    const float* __restrict__ g3, const float* __restrict__ be3,
    const float* __restrict__ W_h2o, const float* __restrict__ b_h2o,
    float* __restrict__ out, float* __restrict__ fws, int T) {
  __shared__ float smem[5552];
  uint32_t* bw = (uint32_t*)(fws + BAR_OFF);
  float* xbuf = fws + XBUF_OFF;
  float* hbuf = fws + H_OFF;
  float* obuf = fws + O_OFF;
  float* si_x = fws + SIX_OFF;     // aliases zbn during setup
  float* gi   = fws + GI_OFF;
  float* gh   = fws + GH_OFF;
  float* gi_z = fws + GIZ_OFF;
  const int blk = blockIdx.x;
  const int tid = threadIdx.x;

  // P0: a = lrelu(z @ W_z2h^T + b_z2h) -> xbuf  (32 blocks)
  if (blk < 32)
    gemm32x64(z, NOISE_SZ, W_z2h, NOISE_SZ, NOISE_SZ, (blk & 3) * 32, (blk >> 2) * 64,
              b_z2h, nullptr, 0, true, xbuf, H, smem);
  gridbar(bw);
  // P1: zbn = BN(a; g1,be1) -> si_x(alias zbn), h0 = zbn
  if (blk < 64) bn8(xbuf, g1, be1, si_x, hbuf, blk * 8);
  gridbar(bw);
  // P2: si_z = BN(zbn; g2[512:], be2[512:]) -> obuf
  if (blk < 64) bn8(si_x, g2 + H, be2 + H, obuf, nullptr, blk * 8);
  gridbar(bw);
  // P3: gi_z = si_z @ W_ih[:,512:]^T + b_ih (96 blocks) || xbuf = lrelu(emb[SOS])
  if (blk < 96) {
    gemm32x64(obuf, H, W_ih + H, 2 * H, H, (blk & 3) * 32, (blk >> 2) * 64,
              b_ih, nullptr, 0, false, gi_z, 1536, smem);
  } else if (blk < 224) {
    const int b = blk - 96;
    const float* er = emb + (size_t)(V_SZ - 1) * H;
    xbuf[(size_t)b * H + tid] = lrelu_(er[tid]);
    xbuf[(size_t)b * H + NTHR + tid] = lrelu_(er[NTHR + tid]);
  }
  gridbar(bw);

  for (int t = 0; t < T; ++t) {
    // A: gh = h @ W_hh^T + b_hh (96 blocks) || si_x = BN(xbuf; g2[:512], be2[:512]) (64 blocks)
    if (blk < 96)
      gemm32x64(hbuf, H, W_hh, H, H, (blk & 3) * 32, (blk >> 2) * 64,
                b_hh, nullptr, 0, false, gh, 1536, smem);
    else if (blk < 160)
      bn8(xbuf, g2, be2, si_x, nullptr, (blk - 96) * 8);
    gridbar(bw);
    // B: gi = si_x @ W_ih[:,:512]^T + gi_z (96 blocks)
    if (blk < 96)
      gemm32x64(si_x, H, W_ih, 2 * H, H, (blk & 3) * 32, (blk >> 2) * 64,
                nullptr, gi_z, 1536, false, gi, 1536, smem);
    gridbar(bw);
    // C: GRU gates + h update + o = BN(lrelu(h)) (64 blocks)
    if (blk < 64) gru8(gi, gh, hbuf, g3, be3, obuf, blk * 8);
    gridbar(bw);
    // D: y = (o @ W_h2o^T + b_h2o + gumbel)/temp -> out rows (252 blocks)
    if (blk < 252)
      gemm32x80_logits(obuf, W_h2o, b_h2o, (blk & 3) * 32, (blk >> 2) * 80,
                       out, t, T, temp, smem);
    gridbar(bw);
    // E: softmax + argmax + gather next embedding (128 blocks)
    if (blk < B_SZ) gumbel_row(out, t, T, blk, emb, xbuf, smem);
    gridbar(bw);
  }
}

// ---------------------------------------------------------------------------
extern "C" void kernel_launch(void* const* d_in, const int* in_sizes, int n_in,
                              void* d_out, int out_size, void* d_ws, size_t ws_size,
                              hipStream_t stream) {
  const float* z     = (const float*)d_in[0];
  const float* temp  = (const float*)d_in[1];
  const float* W_z2h = (const float*)d_in[3];
  const float* b_z2h = (const float*)d_in[4];
  const float* g1    = (const float*)d_in[5];
  const float* be1   = (const float*)d_in[6];
  const float* emb   = (const float*)d_in[7];
  const float* g2    = (const float*)d_in[8];
  const float* be2   = (const float*)d_in[9];
  const float* W_ih  = (const float*)d_in[10];
  const float* b_ih  = (const float*)d_in[11];
  const float* W_hh  = (const float*)d_in[12];
  const float* b_hh  = (const float*)d_in[13];
  const float* g3    = (const float*)d_in[14];
  const float* be3   = (const float*)d_in[15];
  const float* W_h2o = (const float*)d_in[16];
  const float* b_h2o = (const float*)d_in[17];
  float* out = (float*)d_out;
  float* fws = (float*)d_ws;
  const int T = out_size / (B_SZ * V_SZ);   // 128

  // reset barrier state (counters + generation) for deterministic replay
  hipMemsetAsync((void*)((char*)d_ws + (size_t)BAR_OFF * 4), 0, 4096, stream);
  persist<<<NBLK, NTHR, 0, stream>>>(z, temp, W_z2h, b_z2h, g1, be1, emb, g2, be2,
                                     W_ih, b_ih, W_hh, b_hh, g3, be3, W_h2o, b_h2o,
                                     out, fws, T);
}